// Round 19
// baseline (223.353 us; speedup 1.0000x reference)
//
#include <hip/hip_runtime.h>
#include <hip/hip_bf16.h>
#include <stdint.h>

#define B_ 2
#define T_ 2048
#define HID_ 2048
#define H_ 16
#define KVH_ 4
#define D_ 128

typedef __attribute__((ext_vector_type(8))) short short8;
typedef __attribute__((ext_vector_type(4))) float f32x4;

__device__ __forceinline__ uint16_t f2bf(float x) {
  union { float f; uint32_t u; } c; c.f = x;
  uint32_t r = c.u + 0x7fffu + ((c.u >> 16) & 1u);
  return (uint16_t)(r >> 16);
}
__device__ __forceinline__ float bf2f(uint16_t b) {
  union { uint32_t u; float f; } c; c.u = ((uint32_t)b) << 16;
  return c.f;
}
__device__ __forceinline__ uint16_t hwbf(float x) {
  __hip_bfloat16 h = __float2bfloat16(x);
  return *reinterpret_cast<uint16_t*>(&h);
}

// chunk-XOR swizzle for LDS tiles (16B granules), de-aliases r and r+8
#define XM(r) (((r) & 7) ^ (((r) >> 1) & 4))
#define SC_Q 0.1275523865396698f  // 1/sqrt(128) * log2e

// ---------------- merged fp32->bf16 convert + bias concat (one launch) ----------------
__global__ __launch_bounds__(256) void cvt_all(const float* __restrict__ hidden,
                                               const float* __restrict__ Wq,
                                               const float* __restrict__ Wk,
                                               const float* __restrict__ Wv,
                                               const float* __restrict__ Wo,
                                               const float* __restrict__ bq,
                                               const float* __restrict__ bk,
                                               const float* __restrict__ bv,
                                               uint16_t* __restrict__ hidb,
                                               uint16_t* __restrict__ wqkv,
                                               uint16_t* __restrict__ wob,
                                               float* __restrict__ biasq) {
  const int gtid = blockIdx.x * 256 + threadIdx.x;
  const int i = gtid * 4;
  const float* src;
  uint16_t* dst;
  if (i < 8388608)       { src = hidden + i;            dst = hidb + i; }
  else if (i < 12582912) { src = Wq + (i - 8388608);    dst = wqkv + (i - 8388608); }
  else if (i < 13631488) { src = Wk + (i - 12582912);   dst = wqkv + 4194304 + (i - 12582912); }
  else if (i < 14680064) { src = Wv + (i - 13631488);   dst = wqkv + 5242880 + (i - 13631488); }
  else                   { src = Wo + (i - 14680064);   dst = wob + (i - 14680064); }
  const float4 v = *reinterpret_cast<const float4*>(src);
  union { uint16_t s[4]; uint2 u; } pk;
  pk.s[0] = f2bf(v.x); pk.s[1] = f2bf(v.y); pk.s[2] = f2bf(v.z); pk.s[3] = f2bf(v.w);
  *reinterpret_cast<uint2*>(dst) = pk.u;
  if (gtid < 3072)
    biasq[gtid] = (gtid < 2048) ? bq[gtid] : (gtid < 2560) ? bk[gtid - 2048] : bv[gtid - 2560];
}

// ---------------- QKV GEMM: 256x256, 8-phase counted-vmcnt schedule ----------------
// 8 waves as 4M x 2N per phase-quadrant; phase q computes quadrant
// (mh,nh)=(q&1,q>>1) of the current K-tile (16 MFMA). Halves retire early
// (Bh0 after ph1, Ah0 after ph2, Ah1/Bh1 after ph3) -> staging slots:
//   ph0: t(2i+1) Ah1 | ph1: t(2i+1) Bh1 | ph2: t(2i+2) Bh0 | ph3: t(2i+2) Ah0
//   ph4: t(2i+2) Ah1 | ph5: t(2i+2) Bh1 | ph6: t(2i+3) Bh0 | ph7: t(2i+3) Ah0
// Counted s_waitcnt vmcnt(8) BEFORE the end barrier of phases {0,1,3,4,5,7}
// guarantees (with the barrier) that all waves' needed half-tiles landed
// before the next phase's ds_reads. Raw s_barrier (no drain); lgkmcnt(0)+
// sched_barrier before each MFMA burst; setprio around MFMA (T5).
#define QBM 256
#define QBN 256
#define BK 64

__global__ __launch_bounds__(512, 2) void gemm_qkv(const uint16_t* __restrict__ A,
                                                   const uint16_t* __restrict__ Bt,
                                                   const float* __restrict__ bias,
                                                   const float* __restrict__ cosp,
                                                   const float* __restrict__ sinp,
                                                   uint16_t* __restrict__ Qo,
                                                   uint16_t* __restrict__ Ko,
                                                   uint16_t* __restrict__ VtG) {
  __shared__ __align__(16) uint16_t Al[2][QBM * BK];   // 2 x 32 KB
  __shared__ __align__(16) uint16_t Bl[2][QBN * BK];   // 2 x 32 KB (total 128 KB)
  const int K = 2048;
  const int tid = threadIdx.x;
  const int w = tid >> 6;
  const int lane = tid & 63;
  const int wr = w >> 1, wc = w & 1;   // 4 M-waves x 2 N-waves (per quadrant)
  const int lm = lane & 15, lg = lane >> 4;

  // XCD 2D chunk over grid (12,16): orig 0..191; xcd owns 4 Mtiles x 6 Ntiles
  const int orig = blockIdx.y * gridDim.x + blockIdx.x;
  const int xcd = orig & 7;
  const int cc = orig >> 3;
  const int bm = ((xcd & 3) * 4 + (cc & 3)) * QBM;
  const int bn = ((xcd >> 2) * 6 + (cc >> 2)) * QBN;

  f32x4 acc[4][2][4];   // [quadrant q][mi][ni]
  const f32x4 z4 = {0.f, 0.f, 0.f, 0.f};
#pragma unroll
  for (int q = 0; q < 4; ++q)
#pragma unroll
    for (int mi = 0; mi < 2; ++mi)
#pragma unroll
      for (int ni = 0; ni < 4; ++ni) acc[q][mi][ni] = z4;

  // stage one half-tile: 128 rows of A (mat=0) or Bt (mat=1), rows hh*128..,
  // K-cols t*64..; 2 loads/thread, LDS dest linear, global source XOR-swizzled.
  auto stage_half = [&](int buf, int t, int mat, int hh) {
    const int k0 = t * BK;
#pragma unroll
    for (int it = 0; it < 2; ++it) {
      const int chunk = it * 512 + tid;           // 0..1023: local row r, chunk c8
      const int r = chunk >> 3, c8 = chunk & 7;
      const int rr = hh * 128 + r;
      const int csw = (c8 ^ XM(rr)) * 8;
      const uint16_t* g = (mat == 0) ? (A + (size_t)(bm + rr) * K + k0 + csw)
                                     : (Bt + (size_t)(bn + rr) * K + k0 + csw);
      uint16_t* lb = (mat == 0) ? &Al[buf][0] : &Bl[buf][0];
      __builtin_amdgcn_global_load_lds((const __attribute__((address_space(1))) unsigned int*)g,
                                       (__attribute__((address_space(3))) unsigned int*)(lb + (size_t)rr * BK + c8 * 8),
                                       16, 0, 0);
    }
  };

  // prologue: queue order = t0 Bh0, t0 Ah0, t0 Ah1, t0 Bh1, t1 Bh0, t1 Ah0
  stage_half(0, 0, 1, 0);
  stage_half(0, 0, 0, 0);
  stage_half(0, 0, 0, 1);
  stage_half(0, 0, 1, 1);
  stage_half(1, 1, 1, 0);
  stage_half(1, 1, 0, 0);
  asm volatile("s_waitcnt vmcnt(8)" ::: "memory");   // t0 Bh0+Ah0 landed
  __builtin_amdgcn_s_barrier();

  const int nIter = 16;   // 32 K-tiles, 2 per iteration
  for (int i = 0; i < nIter; ++i) {
    const bool lastIt = (i == nIter - 1);
#pragma unroll
    for (int p = 0; p < 8; ++p) {
      const int bufc = p >> 2;          // tile 2i -> buf0, 2i+1 -> buf1
      const int q = p & 3;
      const int mh = q & 1, nh = q >> 1;
      // ds-read this phase's quadrant operands (data guaranteed by the
      // previous phase's vmcnt+barrier)
      short8 af[2][2], bf[4][2];
#pragma unroll
      for (int mi = 0; mi < 2; ++mi)
#pragma unroll
        for (int kk = 0; kk < 2; ++kk) {
          const int row = mh * 128 + wr * 32 + mi * 16 + lm;
          af[mi][kk] = *reinterpret_cast<const short8*>(&Al[bufc][(size_t)row * BK + (((kk * 4 + lg) ^ XM(row)) * 8)]);
        }
#pragma unroll
      for (int ni = 0; ni < 4; ++ni)
#pragma unroll
        for (int kk = 0; kk < 2; ++kk) {
          const int row = nh * 128 + wc * 32 + (ni & 1) * 16 + (ni >> 1) * 64 + lm;
          bf[ni][kk] = *reinterpret_cast<const short8*>(&Bl[bufc][(size_t)row * BK + (((kk * 4 + lg) ^ XM(row)) * 8)]);
        }
      // stage this phase's half-tile (targets only retired halves)
      if (p == 0)      stage_half(1, 2 * i + 1, 0, 1);
      else if (p == 1) stage_half(1, 2 * i + 1, 1, 1);
      else if (!lastIt) {
        if (p == 2)      stage_half(0, 2 * i + 2, 1, 0);
        else if (p == 3) stage_half(0, 2 * i + 2, 0, 0);
        else if (p == 4) stage_half(0, 2 * i + 2, 0, 1);
        else if (p == 5) stage_half(0, 2 * i + 2, 1, 1);
        else if (p == 6) stage_half(1, 2 * i + 3, 1, 0);
        else             stage_half(1, 2 * i + 3, 0, 0);
      }
      __builtin_amdgcn_s_barrier();
      asm volatile("s_waitcnt lgkmcnt(0)" ::: "memory");
      __builtin_amdgcn_sched_barrier(0);
      __builtin_amdgcn_s_setprio(1);
#pragma unroll
      for (int kk = 0; kk < 2; ++kk)
#pragma unroll
        for (int mi = 0; mi < 2; ++mi)
#pragma unroll
          for (int ni = 0; ni < 4; ++ni)
            acc[q][mi][ni] = __builtin_amdgcn_mfma_f32_16x16x32_bf16(af[mi][kk], bf[ni][kk], acc[q][mi][ni], 0, 0, 0);
      __builtin_amdgcn_s_setprio(0);
      // counted vmcnt BEFORE the end barrier (protects next phase's ds_reads)
      if (p == 3) {
        if (lastIt) asm volatile("s_waitcnt vmcnt(0)" ::: "memory");
        else        asm volatile("s_waitcnt vmcnt(8)" ::: "memory");
      } else if (p == 0 || p == 1 || p == 4 || p == 5 || p == 7) {
        asm volatile("s_waitcnt vmcnt(8)" ::: "memory");
      }
      __builtin_amdgcn_s_barrier();
    }
  }

  // ---------------- fused bias + RoPE + scatter epilogue ----------------
  float bb[2][4];
#pragma unroll
  for (int nh = 0; nh < 2; ++nh)
#pragma unroll
    for (int ni = 0; ni < 4; ++ni)
      bb[nh][ni] = bias[bn + nh * 128 + wc * 32 + (ni & 1) * 16 + (ni >> 1) * 64 + lm];

#pragma unroll
  for (int nh = 0; nh < 2; ++nh) {
    const int nb = bn + nh * 128;     // this 128-col head block
    if (nb < 2560) {
      const bool isQ = (nb < 2048);
      const int head = isQ ? (nb >> 7) : ((nb - 2048) >> 7);
      const int nhd = isQ ? H_ : KVH_;
      uint16_t* dst = isQ ? Qo : Ko;
      const float sc = isQ ? SC_Q : 1.0f;
#pragma unroll
      for (int mh = 0; mh < 2; ++mh) {
        const int q = mh + 2 * nh;
#pragma unroll
        for (int mi = 0; mi < 2; ++mi) {
#pragma unroll
          for (int r = 0; r < 4; ++r) {
            const int row = bm + mh * 128 + wr * 32 + mi * 16 + lg * 4 + r;
            const int b = row >> 11, tt = row & 2047;
            const float* cr = cosp + ((size_t)b * T_ + tt) * D_;
            const float* sr = sinp + ((size_t)b * T_ + tt) * D_;
            uint16_t* drow = dst + (((size_t)(b * nhd + head)) * T_ + tt) * D_;
#pragma unroll
            for (int ni = 0; ni < 4; ++ni) {
              const int d = wc * 32 + (ni & 1) * 16 + (ni >> 1) * 64 + lm;
              const float xv = acc[q][mi][ni][r] + bb[nh][ni];
              const float pv = acc[q][mi][ni ^ 2][r] + bb[nh][ni ^ 2];
              const float sgn = (ni < 2) ? -1.f : 1.f;   // ni<2 <=> d<64
              drow[d] = f2bf((xv * cr[d] + sgn * pv * sr[d]) * sc);
            }
          }
        }
      }
    } else {
      const int kvh = (nb - 2560) >> 7;
#pragma unroll
      for (int mh = 0; mh < 2; ++mh) {
        const int q = mh + 2 * nh;
#pragma unroll
        for (int mi = 0; mi < 2; ++mi) {
          const int row0 = bm + mh * 128 + wr * 32 + mi * 16 + lg * 4;
          const int b = row0 >> 11, t0 = row0 & 2047;
#pragma unroll
          for (int ni = 0; ni < 4; ++ni) {
            const int d = wc * 32 + (ni & 1) * 16 + (ni >> 1) * 64 + lm;
            union { uint16_t s[4]; uint2 u; } pk;
#pragma unroll
            for (int r = 0; r < 4; ++r) pk.s[r] = f2bf(acc[q][mi][ni][r] + bb[nh][ni]);
            *reinterpret_cast<uint2*>(VtG + ((size_t)(b * KVH_ + kvh) * D_ + d) * T_ + t0) = pk.u;
          }
        }
      }
    }
  }
}

// ---------------- out-proj GEMM (128^2, 512 thr, 8 waves, 2-phase) ----------------
#define BM 128
#define BN 128

__global__ __launch_bounds__(512, 4) void gemm_bt(const uint16_t* __restrict__ A,
                                                  const uint16_t* __restrict__ Bt,
                                                  float* __restrict__ Cv,
                                                  int M, int N, int K) {
  __shared__ __align__(16) uint16_t Al[2][BM * BK];
  __shared__ __align__(16) uint16_t Bl[2][BN * BK];
  const int tid = threadIdx.x;
  const int w = tid >> 6;
  const int lane = tid & 63;
  const int wr = w >> 1, wc = w & 1;
  const int lm = lane & 15, lg = lane >> 4;

  const int GX = gridDim.x;
  const int orig = blockIdx.y * GX + blockIdx.x;
  const int xcd = orig & 7;
  const int cc = orig >> 3;
  const int bm = ((xcd >> 1) * 8 + (cc & 7)) * BM;
  const int bn = ((xcd & 1) * (GX >> 1) + (cc >> 3)) * BN;

  f32x4 acc[2][4];
  const f32x4 z4 = {0.f, 0.f, 0.f, 0.f};
#pragma unroll
  for (int i = 0; i < 2; ++i)
#pragma unroll
    for (int j = 0; j < 4; ++j) acc[i][j] = z4;

  const int nt = K >> 6;

  auto stage = [&](int b, int t) {
    const int k0 = t * BK;
#pragma unroll
    for (int it = 0; it < 2; ++it) {
      const int chunk = it * 512 + tid;
      const int r = chunk >> 3, c8 = chunk & 7;
      const int csw = (c8 ^ XM(r)) * 8;
      const uint16_t* gA = A + (size_t)(bm + r) * K + k0 + csw;
      const uint16_t* gB = Bt + (size_t)(bn + r) * K + k0 + csw;
      __builtin_amdgcn_global_load_lds((const __attribute__((address_space(1))) unsigned int*)gA,
                                       (__attribute__((address_space(3))) unsigned int*)(&Al[b][0] + chunk * 8),
                                       16, 0, 0);
      __builtin_amdgcn_global_load_lds((const __attribute__((address_space(1))) unsigned int*)gB,
                                       (__attribute__((address_space(3))) unsigned int*)(&Bl[b][0] + chunk * 8),
                                       16, 0, 0);
    }
  };

  stage(0, 0);
  __syncthreads();

  int cur = 0;
  for (int t = 0; t < nt; ++t) {
    if (t + 1 < nt) stage(cur ^ 1, t + 1);
#pragma unroll
    for (int kk = 0; kk < 2; ++kk) {
      short8 af[2], bfr[4];
#pragma unroll
      for (int mi = 0; mi < 2; ++mi) {
        const int r = wr * 32 + mi * 16 + lm;
        af[mi] = *reinterpret_cast<const short8*>(&Al[cur][r * BK + (((kk * 4 + lg) ^ XM(r)) * 8)]);
      }
#pragma unroll
      for (int ni = 0; ni < 4; ++ni) {
        const int r = wc * 64 + ni * 16 + lm;
        bfr[ni] = *reinterpret_cast<const short8*>(&Bl[cur][r * BK + (((kk * 4 + lg) ^ XM(r)) * 8)]);
      }
#pragma unroll
      for (int mi = 0; mi < 2; ++mi)
#pragma unroll
        for (int ni = 0; ni < 4; ++ni)
          acc[mi][ni] = __builtin_amdgcn_mfma_f32_16x16x32_bf16(af[mi], bfr[ni], acc[mi][ni], 0, 0, 0);
    }
    __syncthreads();
    cur ^= 1;
  }

#pragma unroll
  for (int mi = 0; mi < 2; ++mi) {
#pragma unroll
    for (int ni = 0; ni < 4; ++ni) {
      const int col = bn + wc * 64 + ni * 16 + lm;
#pragma unroll
      for (int r = 0; r < 4; ++r) {
        const int row = bm + wr * 32 + mi * 16 + lg * 4 + r;
        Cv[(size_t)row * N + col] = acc[mi][ni][r];
      }
    }
  }
}

// ---------------- causal GQA flash attention (best measured: QBLK=64 paired) ----------------
#define KVBLK 64

__global__ __launch_bounds__(256, 2) void attn_fwd(const uint16_t* __restrict__ Qb,
                                                   const uint16_t* __restrict__ Kb,
                                                   const uint16_t* __restrict__ VtG,
                                                   uint16_t* __restrict__ Ab) {
  __shared__ __align__(16) uint16_t Kl[2][KVBLK * D_];
  __shared__ __align__(16) uint16_t Vtl[2][D_ * KVBLK];
  __shared__ __align__(16) uint16_t Pl[4 * 16 * 64];
  const int tid = threadIdx.x;
  const int w = tid >> 6, lane = tid & 63;
  const int lm = lane & 15, lg = lane >> 4;
  const int bh = blockIdx.y;
  const int b = bh >> 4, h = bh & 15;
  const int kvh = h >> 2;
  const int qtA = (blockIdx.x + bh) & 15;
  const int qtB = 31 - qtA;
  const int nA = qtA + 1;
  const int ntot = 33;

  const uint16_t* Kbase = Kb + ((size_t)(b * KVH_ + kvh)) * T_ * D_;
  const uint16_t* Vtbase = VtG + ((size_t)(b * KVH_ + kvh)) * D_ * T_;
  uint16_t* Pw = Pl + w * 16 * 64;
  const f32x4 z4 = {0.f, 0.f, 0.f, 0.f};

  short8 vone;
#pragma unroll
  for (int j = 0; j < 8; ++j) vone[j] = (short)0x3F80;

  f32x4 o[8];
  f32x4 osum;
  float mrow[4];
  short8 qf[4];

  auto loadQ = [&](int qt) {
    const uint16_t* Qw = Qb + (((size_t)(b * H_ + h)) * T_ + qt * 64 + w * 16) * D_;
#pragma unroll
    for (int kk = 0; kk < 4; ++kk)
      qf[kk] = *reinterpret_cast<const short8*>(Qw + (size_t)lm * D_ + kk * 32 + lg * 8);
  };
  auto resetAcc = [&]() {
#pragma unroll
    for (int f = 0; f < 8; ++f) o[f] = z4;
    osum = z4;
#pragma unroll
    for (int r = 0; r < 4; ++r) mrow[r] = -1e30f;
  };
  auto flush = [&](int qt) {
    const int wr0 = qt * 64 + w * 16;
    float rcp[4];
#pragma unroll
    for (int r = 0; r < 4; ++r) rcp[r] = 1.0f / osum[r];
#pragma unroll
    for (int f = 0; f < 8; ++f) {
      const int col = h * D_ + f * 16 + lm;
#pragma unroll
      for (int r = 0; r < 4; ++r) {
        const int trow = wr0 + lg * 4 + r;
        Ab[((size_t)(b * T_ + trow)) * (H_ * D_) + col] = f2bf(o[f][r] * rcp[r]);
      }
    }
  };
  auto stage = [&](int buf, int kv0) {
#pragma unroll
    for (int it = 0; it < 4; ++it) {
      const int chunk = it * 256 + tid;
      {
        const int r = chunk >> 4, c16 = chunk & 15;
        const uint16_t* g = Kbase + (size_t)(kv0 + r) * D_ + ((c16 ^ XM(r)) * 8);
        __builtin_amdgcn_global_load_lds((const __attribute__((address_space(1))) unsigned int*)g,
                                         (__attribute__((address_space(3))) unsigned int*)(&Kl[buf][0] + (it * 256 + w * 64) * 8),
                                         16, 0, 0);
      }
      {
        const int dd = chunk >> 3, c8 = chunk & 7;
        const uint16_t* g = Vtbase + (size_t)dd * T_ + kv0 + ((c8 ^ XM(dd)) * 8);
        __builtin_amdgcn_global_load_lds((const __attribute__((address_space(1))) unsigned int*)g,
                                         (__attribute__((address_space(3))) unsigned int*)(&Vtl[buf][0] + (it * 256 + w * 64) * 8),
                                         16, 0, 0);
      }
    }
  };

  loadQ(qtA);
  resetAcc();
  stage(0, 0);
  __syncthreads();

  int cur = 0;
  for (int g = 0; g < ntot; ++g) {
    const bool inA = g < nA;
    const int t = inA ? g : g - nA;
    const int qt = inA ? qtA : qtB;
    const int kv0 = t * KVBLK;
    const int wrow0 = qt * 64 + w * 16;

    if (g + 1 < ntot) {
      const int gn = g + 1;
      const int kvn = (gn < nA ? gn : gn - nA) * KVBLK;
      stage(cur ^ 1, kvn);
    }

    f32x4 s[4];
#pragma unroll
    for (int nf = 0; nf < 4; ++nf) s[nf] = z4;
#pragma unroll
    for (int nf = 0; nf < 4; ++nf)
#pragma unroll
      for (int kk = 0; kk < 4; ++kk) {
        const int row = nf * 16 + lm;
        const short8 kf = *reinterpret_cast<const short8*>(&Kl[cur][row * D_ + (((kk * 4 + lg) ^ XM(row)) * 8)]);
        s[nf] = __builtin_amdgcn_mfma_f32_16x16x32_bf16(qf[kk], kf, s[nf], 0, 0, 0);
      }

    if (kv0 + KVBLK - 1 > wrow0) {
#pragma unroll
      for (int nf = 0; nf < 4; ++nf) {
        const int colg = kv0 + nf * 16 + lm;
#pragma unroll
        for (int r = 0; r < 4; ++r) {
          const int rowg = wrow0 + lg * 4 + r;
          if (colg > rowg) s[nf][r] = -1e30f;
        }
      }
    }

    float tmax[4];
#pragma unroll
    for (int r = 0; r < 4; ++r)
      tmax[r] = fmaxf(fmaxf(s[0][r], s[1][r]), fmaxf(s[2][r], s[3][r]));
    bool grow = false;
#pragma unroll
    for (int r = 0; r < 4; ++r) grow = grow || (tmax[r] > mrow[r] + 8.f);
    if (__any((int)grow)) {
#pragma unroll
      for (int r = 0; r < 4; ++r) {
        float v = tmax[r];
        v = fmaxf(v, __shfl_xor(v, 1));
        v = fmaxf(v, __shfl_xor(v, 2));
        v = fmaxf(v, __shfl_xor(v, 4));
        v = fmaxf(v, __shfl_xor(v, 8));
        const float nm = fmaxf(mrow[r], v);
        const float al = exp2f(mrow[r] - nm);
        mrow[r] = nm;
        osum[r] *= al;
#pragma unroll
        for (int f = 0; f < 8; ++f) o[f][r] *= al;
      }
    }
#pragma unroll
    for (int nf = 0; nf < 4; ++nf)
#pragma unroll
      for (int r = 0; r < 4; ++r) {
        const float p = exp2f(s[nf][r] - mrow[r]);
        const int prow = lg * 4 + r;
        const int pchunk = (nf * 2 + (lm >> 3)) ^ XM(prow);
        Pw[prow * 64 + pchunk * 8 + (lm & 7)] = hwbf(p);
      }
    asm volatile("s_waitcnt lgkmcnt(0)" ::: "memory");
    short8 pf[2];
#pragma unroll
    for (int ks = 0; ks < 2; ++ks)
      pf[ks] = *reinterpret_cast<const short8*>(Pw + lm * 64 + (((ks * 4 + lg) ^ XM(lm)) * 8));
#pragma unroll
    for (int ks = 0; ks < 2; ++ks)
      osum = __builtin_amdgcn_mfma_f32_16x16x32_bf16(pf[ks], vone, osum, 0, 0, 0);
#pragma unroll
    for (int f = 0; f < 8; ++f)
#pragma unroll
      for (int ks = 0; ks < 2; ++ks) {
        const int dd = f * 16 + lm;
        const short8 vf = *reinterpret_cast<const short8*>(&Vtl[cur][dd * KVBLK + (((ks * 4 + lg) ^ XM(dd)) * 8)]);
        o[f] = __builtin_amdgcn_mfma_f32_16x16x32_bf16(pf[ks], vf, o[f], 0, 0, 0);
      }

    __syncthreads();
    cur ^= 1;

    if (g == nA - 1) {
      flush(qtA);
      loadQ(qtB);
      resetAcc();
    }
  }
  flush(qtB);
}

// ---------------- launch ----------------
extern "C" void kernel_launch(void* const* d_in, const int* in_sizes, int n_in,
                              void* d_out, int out_size, void* d_ws, size_t ws_size,
                              hipStream_t stream) {
  const float* hidden = (const float*)d_in[0];
  const float* cosp   = (const float*)d_in[1];
  const float* sinp   = (const float*)d_in[2];
  // d_in[3] = attention_mask: exactly causal, implemented in-kernel
  const float* Wq = (const float*)d_in[4];
  const float* bq = (const float*)d_in[5];
  const float* Wk = (const float*)d_in[6];
  const float* bk = (const float*)d_in[7];
  const float* Wv = (const float*)d_in[8];
  const float* bv = (const float*)d_in[9];
  const float* Wo = (const float*)d_in[10];

  char* ws = (char*)d_ws;
  uint16_t* hidb   = (uint16_t*)(ws);              // 4096x2048 bf16   16,777,216 B
  uint16_t* wqkv   = (uint16_t*)(ws + 16777216);   // 3072x2048 bf16   12,582,912 B
  uint16_t* wob    = (uint16_t*)(ws + 29360128);   // 2048x2048 bf16    8,388,608 B
  float*    biasq  = (float*)   (ws + 37748736);   // 3072 f32             12,288 B
  uint16_t* Qb     = (uint16_t*)(ws + 62926848);   // [2][16][2048][128] 16,777,216 B
  uint16_t* Kb     = (uint16_t*)(ws + 79704064);   // [2][4][2048][128]   4,194,304 B
  uint16_t* VtG    = (uint16_t*)(ws + 83898368);   // [2][4][128][2048]   4,194,304 B
  uint16_t* Ab     = (uint16_t*)(ws + 88092672);   // [2][2048][2048]   16,777,216 B

  // one merged convert pass (hidden + Wq/Wk/Wv concat + Wo + bias concat)
  cvt_all<<<18432, 256, 0, stream>>>(hidden, Wq, Wk, Wv, Wo, bq, bk, bv,
                                     hidb, wqkv, wob, biasq);
  // QKV projection (256^2, 8-phase counted-vmcnt) + fused RoPE/scatter/V-transpose
  gemm_qkv<<<dim3(12, 16), 512, 0, stream>>>(hidb, wqkv, biasq, cosp, sinp, Qb, Kb, VtG);
  // causal GQA flash attention -> Ab [b][t][h*128+d] bf16 (paired 64-row q-tiles)
  attn_fwd<<<dim3(16, 32), 256, 0, stream>>>(Qb, Kb, VtG, Ab);
  // output projection: [4096,2048] x [2048,2048]^T -> d_out fp32
  gemm_bt<<<dim3(16, 32), 512, 0, stream>>>(Ab, wob, (float*)d_out, 4096, 2048, 2048);
}

// Round 20
// 197.611 us; speedup vs baseline: 1.1303x; 1.1303x over previous
//
#include <hip/hip_runtime.h>
#include <hip/hip_bf16.h>
#include <stdint.h>

#define B_ 2
#define T_ 2048
#define HID_ 2048
#define H_ 16
#define KVH_ 4
#define D_ 128

typedef __attribute__((ext_vector_type(8))) short short8;
typedef __attribute__((ext_vector_type(4))) float f32x4;

__device__ __forceinline__ uint16_t f2bf(float x) {
  union { float f; uint32_t u; } c; c.f = x;
  uint32_t r = c.u + 0x7fffu + ((c.u >> 16) & 1u);
  return (uint16_t)(r >> 16);
}
__device__ __forceinline__ float bf2f(uint16_t b) {
  union { uint32_t u; float f; } c; c.u = ((uint32_t)b) << 16;
  return c.f;
}
__device__ __forceinline__ uint16_t hwbf(float x) {
  __hip_bfloat16 h = __float2bfloat16(x);
  return *reinterpret_cast<uint16_t*>(&h);
}

// chunk-XOR swizzle for LDS tiles (16B granules), de-aliases r and r+8
#define XM(r) (((r) & 7) ^ (((r) >> 1) & 4))
#define SC_Q 0.1275523865396698f  // 1/sqrt(128) * log2e

// ---------------- merged fp32->bf16 convert + bias concat (one launch) ----------------
__global__ __launch_bounds__(256) void cvt_all(const float* __restrict__ hidden,
                                               const float* __restrict__ Wq,
                                               const float* __restrict__ Wk,
                                               const float* __restrict__ Wv,
                                               const float* __restrict__ Wo,
                                               const float* __restrict__ bq,
                                               const float* __restrict__ bk,
                                               const float* __restrict__ bv,
                                               uint16_t* __restrict__ hidb,
                                               uint16_t* __restrict__ wqkv,
                                               uint16_t* __restrict__ wob,
                                               float* __restrict__ biasq) {
  const int gtid = blockIdx.x * 256 + threadIdx.x;
  const int i = gtid * 4;
  const float* src;
  uint16_t* dst;
  if (i < 8388608)       { src = hidden + i;            dst = hidb + i; }
  else if (i < 12582912) { src = Wq + (i - 8388608);    dst = wqkv + (i - 8388608); }
  else if (i < 13631488) { src = Wk + (i - 12582912);   dst = wqkv + 4194304 + (i - 12582912); }
  else if (i < 14680064) { src = Wv + (i - 13631488);   dst = wqkv + 5242880 + (i - 13631488); }
  else                   { src = Wo + (i - 14680064);   dst = wob + (i - 14680064); }
  const float4 v = *reinterpret_cast<const float4*>(src);
  union { uint16_t s[4]; uint2 u; } pk;
  pk.s[0] = f2bf(v.x); pk.s[1] = f2bf(v.y); pk.s[2] = f2bf(v.z); pk.s[3] = f2bf(v.w);
  *reinterpret_cast<uint2*>(dst) = pk.u;
  if (gtid < 3072)
    biasq[gtid] = (gtid < 2048) ? bq[gtid] : (gtid < 2560) ? bk[gtid - 2048] : bv[gtid - 2560];
}

// ---------------- QKV GEMM: 256x256 tile, BK=64, 512 thr, 2-phase (round-18 best) ----------------
#define QBM 256
#define QBN 256
#define BK 64

__global__ __launch_bounds__(512, 2) void gemm_qkv(const uint16_t* __restrict__ A,
                                                   const uint16_t* __restrict__ Bt,
                                                   const float* __restrict__ bias,
                                                   const float* __restrict__ cosp,
                                                   const float* __restrict__ sinp,
                                                   uint16_t* __restrict__ Qo,
                                                   uint16_t* __restrict__ Ko,
                                                   uint16_t* __restrict__ VtG) {
  __shared__ __align__(16) uint16_t Al[2][QBM * BK];   // 2 x 32 KB
  __shared__ __align__(16) uint16_t Bl[2][QBN * BK];   // 2 x 32 KB (total 128 KB)
  const int K = 2048;
  const int tid = threadIdx.x;
  const int w = tid >> 6;
  const int lane = tid & 63;
  const int wr = w >> 2, wc = w & 3;   // 2 M-waves x 4 N-waves; wave tile 128x64
  const int lm = lane & 15, lg = lane >> 4;

  // XCD 2D chunk over grid (12,16): orig 0..191; xcd owns 4 Mtiles x 6 Ntiles
  const int orig = blockIdx.y * gridDim.x + blockIdx.x;
  const int xcd = orig & 7;
  const int cc = orig >> 3;            // 0..23
  const int bm = ((xcd & 3) * 4 + (cc & 3)) * QBM;
  const int bn = ((xcd >> 2) * 6 + (cc >> 2)) * QBN;

  // B-frag col-base per ni (RoPE partner d^64 = frag ni^2, same thread)
  const int cb0 = (wc >> 1) * 128 + (wc & 1) * 32;
  const int colb[4] = {cb0, cb0 + 16, cb0 + 64, cb0 + 80};

  f32x4 acc[8][4];
  const f32x4 z4 = {0.f, 0.f, 0.f, 0.f};
#pragma unroll
  for (int i = 0; i < 8; ++i)
#pragma unroll
    for (int j = 0; j < 4; ++j) acc[i][j] = z4;

  const int nt = K >> 6;   // 32

  auto stage = [&](int b, int t) {
    const int k0 = t * BK;
#pragma unroll
    for (int it = 0; it < 4; ++it) {
      const int chunk = it * 512 + tid;          // 0..2047 (row r, 16B chunk c8)
      const int r = chunk >> 3, c8 = chunk & 7;
      const int csw = (c8 ^ XM(r)) * 8;
      const uint16_t* gA = A + (size_t)(bm + r) * K + k0 + csw;
      const uint16_t* gB = Bt + (size_t)(bn + r) * K + k0 + csw;
      __builtin_amdgcn_global_load_lds((const __attribute__((address_space(1))) unsigned int*)gA,
                                       (__attribute__((address_space(3))) unsigned int*)(&Al[b][0] + chunk * 8),
                                       16, 0, 0);
      __builtin_amdgcn_global_load_lds((const __attribute__((address_space(1))) unsigned int*)gB,
                                       (__attribute__((address_space(3))) unsigned int*)(&Bl[b][0] + chunk * 8),
                                       16, 0, 0);
    }
  };

  stage(0, 0);
  __syncthreads();

  int cur = 0;
  for (int t = 0; t < nt; ++t) {
    if (t + 1 < nt) stage(cur ^ 1, t + 1);
#pragma unroll
    for (int kk = 0; kk < 2; ++kk) {
      short8 bfr[4];
#pragma unroll
      for (int ni = 0; ni < 4; ++ni) {
        const int rb = colb[ni] + lm;
        bfr[ni] = *reinterpret_cast<const short8*>(&Bl[cur][rb * BK + (((kk * 4 + lg) ^ XM(rb)) * 8)]);
      }
#pragma unroll
      for (int mi = 0; mi < 8; ++mi) {
        const int r = wr * 128 + mi * 16 + lm;
        const short8 af = *reinterpret_cast<const short8*>(&Al[cur][r * BK + (((kk * 4 + lg) ^ XM(r)) * 8)]);
#pragma unroll
        for (int ni = 0; ni < 4; ++ni)
          acc[mi][ni] = __builtin_amdgcn_mfma_f32_16x16x32_bf16(af, bfr[ni], acc[mi][ni], 0, 0, 0);
      }
    }
    __syncthreads();
    cur ^= 1;
  }

  float bb[4];
#pragma unroll
  for (int ni = 0; ni < 4; ++ni) bb[ni] = bias[bn + colb[ni] + lm];

  if (bn < 2560) {
    // Q (bn<2048) or K: bias -> RoPE -> (SC_Q for Q) -> scatter
    const bool isQ = (bn < 2048);
    const int head0 = (isQ ? (bn >> 7) : ((bn - 2048) >> 7)) + (wc >> 1);
    const int nh = isQ ? H_ : KVH_;
    uint16_t* dst = isQ ? Qo : Ko;
    const float sc = isQ ? SC_Q : 1.0f;
#pragma unroll
    for (int mi = 0; mi < 8; ++mi) {
#pragma unroll
      for (int r = 0; r < 4; ++r) {
        const int row = bm + wr * 128 + mi * 16 + lg * 4 + r;
        const int b = row >> 11, tt = row & 2047;
        const float* cr = cosp + ((size_t)b * T_ + tt) * D_;
        const float* sr = sinp + ((size_t)b * T_ + tt) * D_;
        uint16_t* drow = dst + (((size_t)(b * nh + head0)) * T_ + tt) * D_;
#pragma unroll
        for (int ni = 0; ni < 4; ++ni) {
          const int d = (wc & 1) * 32 + (ni & 1) * 16 + (ni >> 1) * 64 + lm;
          const float xv = acc[mi][ni][r] + bb[ni];
          const float pv = acc[mi][ni ^ 2][r] + bb[ni ^ 2];
          const float sgn = (ni < 2) ? -1.f : 1.f;  // ni<2 <=> d<64
          drow[d] = f2bf((xv * cr[d] + sgn * pv * sr[d]) * sc);
        }
      }
    }
  } else {
    // V: bias -> transposed write VtG[(b*4+kvh)*128+d][t], 4 bf16 packed (8B)
    const int kvh = ((bn - 2560) >> 7) + (wc >> 1);
#pragma unroll
    for (int mi = 0; mi < 8; ++mi) {
      const int row0 = bm + wr * 128 + mi * 16 + lg * 4;
      const int b = row0 >> 11, t0 = row0 & 2047;
#pragma unroll
      for (int ni = 0; ni < 4; ++ni) {
        const int d = (wc & 1) * 32 + (ni & 1) * 16 + (ni >> 1) * 64 + lm;
        union { uint16_t s[4]; uint2 u; } pk;
#pragma unroll
        for (int r = 0; r < 4; ++r) pk.s[r] = f2bf(acc[mi][ni][r] + bb[ni]);
        *reinterpret_cast<uint2*>(VtG + ((size_t)(b * KVH_ + kvh) * D_ + d) * T_ + t0) = pk.u;
      }
    }
  }
}

// ---------------- out-proj GEMM (128^2, 512 thr, 8 waves, 2-phase) ----------------
#define BM 128
#define BN 128

__global__ __launch_bounds__(512, 4) void gemm_bt(const uint16_t* __restrict__ A,
                                                  const uint16_t* __restrict__ Bt,
                                                  float* __restrict__ Cv,
                                                  int M, int N, int K) {
  __shared__ __align__(16) uint16_t Al[2][BM * BK];
  __shared__ __align__(16) uint16_t Bl[2][BN * BK];
  const int tid = threadIdx.x;
  const int w = tid >> 6;
  const int lane = tid & 63;
  const int wr = w >> 1, wc = w & 1;
  const int lm = lane & 15, lg = lane >> 4;

  // XCD 2D chunk for grid (16,32): xcd owns 8 Mtiles x 8 Ntiles, M-fastest
  const int GX = gridDim.x;
  const int orig = blockIdx.y * GX + blockIdx.x;
  const int xcd = orig & 7;
  const int cc = orig >> 3;
  const int bm = ((xcd >> 1) * 8 + (cc & 7)) * BM;
  const int bn = ((xcd & 1) * (GX >> 1) + (cc >> 3)) * BN;

  f32x4 acc[2][4];
  const f32x4 z4 = {0.f, 0.f, 0.f, 0.f};
#pragma unroll
  for (int i = 0; i < 2; ++i)
#pragma unroll
    for (int j = 0; j < 4; ++j) acc[i][j] = z4;

  const int nt = K >> 6;

  auto stage = [&](int b, int t) {
    const int k0 = t * BK;
#pragma unroll
    for (int it = 0; it < 2; ++it) {
      const int chunk = it * 512 + tid;
      const int r = chunk >> 3, c8 = chunk & 7;
      const int csw = (c8 ^ XM(r)) * 8;
      const uint16_t* gA = A + (size_t)(bm + r) * K + k0 + csw;
      const uint16_t* gB = Bt + (size_t)(bn + r) * K + k0 + csw;
      __builtin_amdgcn_global_load_lds((const __attribute__((address_space(1))) unsigned int*)gA,
                                       (__attribute__((address_space(3))) unsigned int*)(&Al[b][0] + chunk * 8),
                                       16, 0, 0);
      __builtin_amdgcn_global_load_lds((const __attribute__((address_space(1))) unsigned int*)gB,
                                       (__attribute__((address_space(3))) unsigned int*)(&Bl[b][0] + chunk * 8),
                                       16, 0, 0);
    }
  };

  stage(0, 0);
  __syncthreads();

  int cur = 0;
  for (int t = 0; t < nt; ++t) {
    if (t + 1 < nt) stage(cur ^ 1, t + 1);
#pragma unroll
    for (int kk = 0; kk < 2; ++kk) {
      short8 af[2], bfr[4];
#pragma unroll
      for (int mi = 0; mi < 2; ++mi) {
        const int r = wr * 32 + mi * 16 + lm;
        af[mi] = *reinterpret_cast<const short8*>(&Al[cur][r * BK + (((kk * 4 + lg) ^ XM(r)) * 8)]);
      }
#pragma unroll
      for (int ni = 0; ni < 4; ++ni) {
        const int r = wc * 64 + ni * 16 + lm;
        bfr[ni] = *reinterpret_cast<const short8*>(&Bl[cur][r * BK + (((kk * 4 + lg) ^ XM(r)) * 8)]);
      }
#pragma unroll
      for (int mi = 0; mi < 2; ++mi)
#pragma unroll
        for (int ni = 0; ni < 4; ++ni)
          acc[mi][ni] = __builtin_amdgcn_mfma_f32_16x16x32_bf16(af[mi], bfr[ni], acc[mi][ni], 0, 0, 0);
    }
    __syncthreads();
    cur ^= 1;
  }

#pragma unroll
  for (int mi = 0; mi < 2; ++mi) {
#pragma unroll
    for (int ni = 0; ni < 4; ++ni) {
      const int col = bn + wc * 64 + ni * 16 + lm;
#pragma unroll
      for (int r = 0; r < 4; ++r) {
        const int row = bm + wr * 32 + mi * 16 + lg * 4 + r;
        Cv[(size_t)row * N + col] = acc[mi][ni][r];
      }
    }
  }
}

// ---------------- causal GQA flash attention (QBLK=64 paired; XCD-grouped KV) ----------------
// 1-D grid of 512. blockIdx%8 = KV group (b,kvh) -> all 64 blocks sharing a
// 2.1MB K+V panel land on one XCD (dispatch round-robin heuristic) for L2 reuse.
#define KVBLK 64

__global__ __launch_bounds__(256, 2) void attn_fwd(const uint16_t* __restrict__ Qb,
                                                   const uint16_t* __restrict__ Kb,
                                                   const uint16_t* __restrict__ VtG,
                                                   uint16_t* __restrict__ Ab) {
  __shared__ __align__(16) uint16_t Kl[2][KVBLK * D_];
  __shared__ __align__(16) uint16_t Vtl[2][D_ * KVBLK];
  __shared__ __align__(16) uint16_t Pl[4 * 16 * 64];
  const int tid = threadIdx.x;
  const int w = tid >> 6, lane = tid & 63;
  const int lm = lane & 15, lg = lane >> 4;
  // relabel: grp = (b,kvh) KV group on one XCD; i = position within group
  const int grp = blockIdx.x & 7;          // 0..7
  const int i0 = blockIdx.x >> 3;          // 0..63
  const int b = grp >> 2, kvh = grp & 3;
  const int h = kvh * 4 + (i0 >> 4);
  const int bh = b * 16 + h;
  const int x = i0 & 15;
  const int qtA = (x + bh) & 15;
  const int qtB = 31 - qtA;
  const int nA = qtA + 1;
  const int ntot = 33;

  const uint16_t* Kbase = Kb + ((size_t)(b * KVH_ + kvh)) * T_ * D_;
  const uint16_t* Vtbase = VtG + ((size_t)(b * KVH_ + kvh)) * D_ * T_;
  uint16_t* Pw = Pl + w * 16 * 64;
  const f32x4 z4 = {0.f, 0.f, 0.f, 0.f};

  short8 vone;
#pragma unroll
  for (int j = 0; j < 8; ++j) vone[j] = (short)0x3F80;

  f32x4 o[8];
  f32x4 osum;
  float mrow[4];
  short8 qf[4];

  auto loadQ = [&](int qt) {
    const uint16_t* Qw = Qb + (((size_t)(b * H_ + h)) * T_ + qt * 64 + w * 16) * D_;
#pragma unroll
    for (int kk = 0; kk < 4; ++kk)
      qf[kk] = *reinterpret_cast<const short8*>(Qw + (size_t)lm * D_ + kk * 32 + lg * 8);
  };
  auto resetAcc = [&]() {
#pragma unroll
    for (int f = 0; f < 8; ++f) o[f] = z4;
    osum = z4;
#pragma unroll
    for (int r = 0; r < 4; ++r) mrow[r] = -1e30f;
  };
  auto flush = [&](int qt) {
    const int wr0 = qt * 64 + w * 16;
    float rcp[4];
#pragma unroll
    for (int r = 0; r < 4; ++r) rcp[r] = 1.0f / osum[r];
#pragma unroll
    for (int f = 0; f < 8; ++f) {
      const int col = h * D_ + f * 16 + lm;
#pragma unroll
      for (int r = 0; r < 4; ++r) {
        const int trow = wr0 + lg * 4 + r;
        Ab[((size_t)(b * T_ + trow)) * (H_ * D_) + col] = f2bf(o[f][r] * rcp[r]);
      }
    }
  };
  auto stage = [&](int buf, int kv0) {
#pragma unroll
    for (int it = 0; it < 4; ++it) {
      const int chunk = it * 256 + tid;
      {
        const int r = chunk >> 4, c16 = chunk & 15;
        const uint16_t* g = Kbase + (size_t)(kv0 + r) * D_ + ((c16 ^ XM(r)) * 8);
        __builtin_amdgcn_global_load_lds((const __attribute__((address_space(1))) unsigned int*)g,
                                         (__attribute__((address_space(3))) unsigned int*)(&Kl[buf][0] + (it * 256 + w * 64) * 8),
                                         16, 0, 0);
      }
      {
        const int dd = chunk >> 3, c8 = chunk & 7;
        const uint16_t* g = Vtbase + (size_t)dd * T_ + kv0 + ((c8 ^ XM(dd)) * 8);
        __builtin_amdgcn_global_load_lds((const __attribute__((address_space(1))) unsigned int*)g,
                                         (__attribute__((address_space(3))) unsigned int*)(&Vtl[buf][0] + (it * 256 + w * 64) * 8),
                                         16, 0, 0);
      }
    }
  };

  loadQ(qtA);
  resetAcc();
  stage(0, 0);
  __syncthreads();

  int cur = 0;
  for (int g = 0; g < ntot; ++g) {
    const bool inA = g < nA;
    const int t = inA ? g : g - nA;
    const int qt = inA ? qtA : qtB;
    const int kv0 = t * KVBLK;
    const int wrow0 = qt * 64 + w * 16;

    if (g + 1 < ntot) {
      const int gn = g + 1;
      const int kvn = (gn < nA ? gn : gn - nA) * KVBLK;
      stage(cur ^ 1, kvn);
    }

    f32x4 s[4];
#pragma unroll
    for (int nf = 0; nf < 4; ++nf) s[nf] = z4;
#pragma unroll
    for (int nf = 0; nf < 4; ++nf)
#pragma unroll
      for (int kk = 0; kk < 4; ++kk) {
        const int row = nf * 16 + lm;
        const short8 kf = *reinterpret_cast<const short8*>(&Kl[cur][row * D_ + (((kk * 4 + lg) ^ XM(row)) * 8)]);
        s[nf] = __builtin_amdgcn_mfma_f32_16x16x32_bf16(qf[kk], kf, s[nf], 0, 0, 0);
      }

    if (kv0 + KVBLK - 1 > wrow0) {
#pragma unroll
      for (int nf = 0; nf < 4; ++nf) {
        const int colg = kv0 + nf * 16 + lm;
#pragma unroll
        for (int r = 0; r < 4; ++r) {
          const int rowg = wrow0 + lg * 4 + r;
          if (colg > rowg) s[nf][r] = -1e30f;
        }
      }
    }

    float tmax[4];
#pragma unroll
    for (int r = 0; r < 4; ++r)
      tmax[r] = fmaxf(fmaxf(s[0][r], s[1][r]), fmaxf(s[2][r], s[3][r]));
    bool grow = false;
#pragma unroll
    for (int r = 0; r < 4; ++r) grow = grow || (tmax[r] > mrow[r] + 8.f);
    if (__any((int)grow)) {
#pragma unroll
      for (int r = 0; r < 4; ++r) {
        float v = tmax[r];
        v = fmaxf(v, __shfl_xor(v, 1));
        v = fmaxf(v, __shfl_xor(v, 2));
        v = fmaxf(v, __shfl_xor(v, 4));
        v = fmaxf(v, __shfl_xor(v, 8));
        const float nm = fmaxf(mrow[r], v);
        const float al = exp2f(mrow[r] - nm);
        mrow[r] = nm;
        osum[r] *= al;
#pragma unroll
        for (int f = 0; f < 8; ++f) o[f][r] *= al;
      }
    }
#pragma unroll
    for (int nf = 0; nf < 4; ++nf)
#pragma unroll
      for (int r = 0; r < 4; ++r) {
        const float p = exp2f(s[nf][r] - mrow[r]);
        const int prow = lg * 4 + r;
        const int pchunk = (nf * 2 + (lm >> 3)) ^ XM(prow);
        Pw[prow * 64 + pchunk * 8 + (lm & 7)] = hwbf(p);
      }
    asm volatile("s_waitcnt lgkmcnt(0)" ::: "memory");
    short8 pf[2];
#pragma unroll
    for (int ks = 0; ks < 2; ++ks)
      pf[ks] = *reinterpret_cast<const short8*>(Pw + lm * 64 + (((ks * 4 + lg) ^ XM(lm)) * 8));
#pragma unroll
    for (int ks = 0; ks < 2; ++ks)
      osum = __builtin_amdgcn_mfma_f32_16x16x32_bf16(pf[ks], vone, osum, 0, 0, 0);
#pragma unroll
    for (int f = 0; f < 8; ++f)
#pragma unroll
      for (int ks = 0; ks < 2; ++ks) {
        const int dd = f * 16 + lm;
        const short8 vf = *reinterpret_cast<const short8*>(&Vtl[cur][dd * KVBLK + (((ks * 4 + lg) ^ XM(dd)) * 8)]);
        o[f] = __builtin_amdgcn_mfma_f32_16x16x32_bf16(pf[ks], vf, o[f], 0, 0, 0);
      }

    __syncthreads();
    cur ^= 1;

    if (g == nA - 1) {
      flush(qtA);
      loadQ(qtB);
      resetAcc();
    }
  }
  flush(qtB);
}

// ---------------- launch ----------------
extern "C" void kernel_launch(void* const* d_in, const int* in_sizes, int n_in,
                              void* d_out, int out_size, void* d_ws, size_t ws_size,
                              hipStream_t stream) {
  const float* hidden = (const float*)d_in[0];
  const float* cosp   = (const float*)d_in[1];
  const float* sinp   = (const float*)d_in[2];
  // d_in[3] = attention_mask: exactly causal, implemented in-kernel
  const float* Wq = (const float*)d_in[4];
  const float* bq = (const float*)d_in[5];
  const float* Wk = (const float*)d_in[6];
  const float* bk = (const float*)d_in[7];
  const float* Wv = (const float*)d_in[8];
  const float* bv = (const float*)d_in[9];
  const float* Wo = (const float*)d_in[10];

  char* ws = (char*)d_ws;
  uint16_t* hidb   = (uint16_t*)(ws);              // 4096x2048 bf16   16,777,216 B
  uint16_t* wqkv   = (uint16_t*)(ws + 16777216);   // 3072x2048 bf16   12,582,912 B
  uint16_t* wob    = (uint16_t*)(ws + 29360128);   // 2048x2048 bf16    8,388,608 B
  float*    biasq  = (float*)   (ws + 37748736);   // 3072 f32             12,288 B
  uint16_t* Qb     = (uint16_t*)(ws + 62926848);   // [2][16][2048][128] 16,777,216 B
  uint16_t* Kb     = (uint16_t*)(ws + 79704064);   // [2][4][2048][128]   4,194,304 B
  uint16_t* VtG    = (uint16_t*)(ws + 83898368);   // [2][4][128][2048]   4,194,304 B
  uint16_t* Ab     = (uint16_t*)(ws + 88092672);   // [2][2048][2048]   16,777,216 B

  // one merged convert pass (hidden + Wq/Wk/Wv concat + Wo + bias concat)
  cvt_all<<<18432, 256, 0, stream>>>(hidden, Wq, Wk, Wv, Wo, bq, bk, bv,
                                     hidb, wqkv, wob, biasq);
  // QKV projection (256^2 tile, 2-phase) with fused bias+RoPE/scatter/V-transpose
  gemm_qkv<<<dim3(12, 16), 512, 0, stream>>>(hidb, wqkv, biasq, cosp, sinp, Qb, Kb, VtG);
  // causal GQA flash attention -> Ab (XCD-grouped KV, paired 64-row q-tiles)
  attn_fwd<<<512, 256, 0, stream>>>(Qb, Kb, VtG, Ab);
  // output projection: [4096,2048] x [2048,2048]^T -> d_out fp32
  gemm_bt<<<dim3(16, 32), 512, 0, stream>>>(Ab, wob, (float*)d_out, 4096, 2048, 2048);
}